// Round 7
// baseline (262.211 us; speedup 1.0000x reference)
//
#include <hip/hip_runtime.h>
#include <hip/hip_bf16.h>

#define L2E 1.4426950408889634f
#define LN2 0.6931471805599453f

__device__ __forceinline__ float fexp2(float x) { return __builtin_amdgcn_exp2f(x); }
__device__ __forceinline__ float flog2(float x) { return __builtin_amdgcn_logf(x); }
__device__ __forceinline__ int uniform(int x) { return __builtin_amdgcn_readfirstlane(x); }
__device__ __forceinline__ float sigmoidf_(float v) { return 1.f / (1.f + fexp2(-v * L2E)); }
__device__ __forceinline__ float softplusf_(float t) {
    return (t > 20.f) ? t : LN2 * flog2(1.f + fexp2(t * L2E));
}

// ---------------- workspace layout (floats) ----------------
constexpr size_t O_M   = 0;          // [32][1024] LN mean
constexpr size_t O_RS  = 32768;      // [32][1024] LN rstd
constexpr size_t O_Z   = 65536;      // [32][128][1024] z
constexpr size_t O_XC  = 4259840;    // [32][128][1024] conv+silu out
constexpr size_t O_BM  = 8454144;    // [32][16][1024]
constexpr size_t O_CM  = 8978432;    // [32][16][1024]
constexpr size_t O_DTP = 9502720;    // [32][4][1024] dt-proj pre-softplus planes
constexpr size_t O_HP  = 9633792;    // [32][32][2][2048] per-chunk P(->h_init) and E

// ================= kA: LN + in-proj + conv/SiLU + x-proj (fused) =================
// grid 512 = 32 seq * 16 ptile (64 cols); block 256 = 4 waves.
// All GEMM weights staged in LDS, read as wave-uniform b128 broadcasts.
__global__ __launch_bounds__(256) void kA_front(
    const float* __restrict__ x0, const float* __restrict__ x1,
    const float* __restrict__ x2, const float* __restrict__ x3,
    const float* __restrict__ win,
    const float* __restrict__ g1, const float* __restrict__ be1,
    const float* __restrict__ g2, const float* __restrict__ be2,
    const float* __restrict__ g3, const float* __restrict__ be3,
    const float* __restrict__ g4, const float* __restrict__ be4,
    const float* __restrict__ wconv, const float* __restrict__ bconv,
    const float* __restrict__ wxp, float* __restrict__ ws)
{
    __shared__ __align__(16) float sXI[128 * 68];  // xi -> xc [d][64 main + 3 halo]
    __shared__ __align__(16) float sU[8704];       // union: sX(64x68) + sW chunk(64x68); later sWx[36][128]
    __shared__ __align__(16) float sWc[512];
    __shared__ float sBc[128];
    __shared__ float sPs[256], sPq[256];
    __shared__ float sM[68], sR[68];
    float* sX  = sU;            // 64*68 = 4352
    float* sW  = sU + 4352;     // 64*68 = 4352
    float* sWx = sU;            // 36*128 = 4608 (overlay after in-proj/halo)

    int bid = blockIdx.x;
    int seq = bid >> 4, ptile = bid & 15;
    int branch = seq >> 3, b = seq & 7;
    int tid = threadIdx.x;
    int lane = tid & 63;
    int wq = uniform(tid >> 6);
    int p0 = ptile * 64;
    const float* xin = (branch==0)?x0:(branch==1)?x1:(branch==2)?x2:x3;
    const float* gam = (branch==0)?g1:(branch==1)?g2:(branch==2)?g3:g4;
    const float* bet = (branch==0)?be1:(branch==1)?be2:(branch==2)?be3:be4;
    const float* xb = xin + (size_t)b * 65536;

    // ---- stage conv weights + raw x (main + 3 halo cols) ----
    for (int i = tid; i < 512; i += 256) sWc[i] = wconv[i];
    if (tid < 128) sBc[tid] = bconv[tid];
#pragma unroll
    for (int k = 0; k < 4; ++k) {
        int i = tid + k * 256;
        int c = i >> 4, p4 = (i & 15) * 4;
        *(float4*)&sX[c * 68 + p4] = *(const float4*)&xb[(size_t)c * 1024 + p0 + p4];
    }
    if (ptile > 0) {
        int hc = tid & 3, c = tid >> 2;
        if (hc < 3) sX[c * 68 + 64 + hc] = xb[(size_t)c * 1024 + p0 - 3 + hc];
    }
    __syncthreads();
    // ---- LN stats: main cols two-level; halo cols per-wave shuffle ----
    {
        float s = 0.f, q = 0.f;
#pragma unroll
        for (int cc = 0; cc < 16; ++cc) {
            float v = sX[(wq * 16 + cc) * 68 + lane];
            s += v; q += v * v;
        }
        sPs[wq * 64 + lane] = s; sPq[wq * 64 + lane] = q;
    }
    if (ptile > 0 && wq < 3) {   // whole wave participates in shuffle
        float v = sX[lane * 68 + 64 + wq];
        float s = v, q = v * v;
#pragma unroll
        for (int off = 1; off < 64; off <<= 1) {
            s += __shfl_xor(s, off);
            q += __shfl_xor(q, off);
        }
        if (lane == 0) {
            float mean = s * (1.f/64.f);
            float var  = q * (1.f/64.f) - mean * mean;
            sM[64 + wq] = mean; sR[64 + wq] = rsqrtf(var + 1e-5f);
        }
    }
    __syncthreads();
    if (tid < 64) {
        float ss = sPs[tid] + sPs[64 + tid] + sPs[128 + tid] + sPs[192 + tid];
        float qq = sPq[tid] + sPq[64 + tid] + sPq[128 + tid] + sPq[192 + tid];
        float mean = ss * (1.f/64.f);
        float var  = qq * (1.f/64.f) - mean * mean;
        float rs   = rsqrtf(var + 1e-5f);
        sM[tid] = mean; sR[tid] = rs;
        ws[O_M  + (size_t)seq * 1024 + p0 + tid] = mean;
        ws[O_RS + (size_t)seq * 1024 + p0 + tid] = rs;
    }
    __syncthreads();
    // ---- normalize: main (c uniform per wave) + halo ----
    {
        float mean = sM[lane], rs = sR[lane];
#pragma unroll
        for (int k = 0; k < 16; ++k) {
            int c = wq + k * 4;                          // uniform
            float v = sX[c * 68 + lane];
            sX[c * 68 + lane] = (v - mean) * rs * gam[c] + bet[c];
        }
    }
    if (ptile > 0 && wq < 3) {
        int col = 64 + wq;
        float mean = sM[col], rs = sR[col];
        float v = sX[lane * 68 + col];
        sX[lane * 68 + col] = (v - mean) * rs * gam[lane] + bet[lane];
    }
    __syncthreads();
    // ---- in-proj: 4 chunks of 64 j; weights LDS-staged, uniform b128 reads ----
    float* zz = ws + O_Z + (size_t)seq * 131072;
    for (int ck = 0; ck < 4; ++ck) {
#pragma unroll
        for (int k = 0; k < 4; ++k) {
            int i = tid + k * 256;
            int jr = i >> 4, c4 = (i & 15) * 4;
            *(float4*)&sW[jr * 68 + c4] = *(const float4*)&win[(size_t)(ck * 64 + jr) * 64 + c4];
        }
        __syncthreads();
        float acc[16];
#pragma unroll
        for (int jj = 0; jj < 16; ++jj) acc[jj] = 0.f;
        int jr0 = wq * 16;                               // uniform
#pragma unroll 4
        for (int c4 = 0; c4 < 16; ++c4) {
            float xv0 = sX[(c4*4+0) * 68 + lane];
            float xv1 = sX[(c4*4+1) * 68 + lane];
            float xv2 = sX[(c4*4+2) * 68 + lane];
            float xv3 = sX[(c4*4+3) * 68 + lane];
#pragma unroll
            for (int jj = 0; jj < 16; ++jj) {
                float4 w4 = *(const float4*)&sW[(jr0 + jj) * 68 + c4 * 4];  // uniform broadcast
                acc[jj] += xv0*w4.x + xv1*w4.y + xv2*w4.z + xv3*w4.w;
            }
        }
        int jg0 = ck * 64 + jr0;
#pragma unroll
        for (int jj = 0; jj < 16; ++jj) {
            int j = jg0 + jj;
            if (j < 128) sXI[j * 68 + lane] = acc[jj];
            else         zz[(size_t)(j - 128) * 1024 + p0 + lane] = acc[jj];
        }
        __syncthreads();
    }
    // ---- halo xi (3 cols x 128 j) via shuffle reduce, or zero-fill ----
    if (ptile > 0) {
        for (int jj = 0; jj < 32; ++jj) {
            int j = wq * 32 + jj;                        // uniform
            float wv = win[(size_t)j * 64 + lane];       // coalesced
            float a0 = wv * sX[lane * 68 + 64];
            float a1 = wv * sX[lane * 68 + 65];
            float a2v = wv * sX[lane * 68 + 66];
#pragma unroll
            for (int off = 1; off < 64; off <<= 1) {
                a0  += __shfl_xor(a0,  off);
                a1  += __shfl_xor(a1,  off);
                a2v += __shfl_xor(a2v, off);
            }
            if (lane == 0) {
                sXI[j * 68 + 64] = a0;
                sXI[j * 68 + 65] = a1;
                sXI[j * 68 + 66] = a2v;
            }
        }
    } else {
#pragma unroll
        for (int k = 0; k < 2; ++k) {
            int d = (tid >> 2) + k * 64, hc = tid & 3;
            if (hc < 3) sXI[d * 68 + 64 + hc] = 0.f;
        }
    }
    __syncthreads();
    // ---- overlay-stage x-proj weights + conv4 + SiLU in place ----
#pragma unroll
    for (int k = 0; k < 5; ++k) {
        int i = tid + k * 256;
        if (i < 1152) {
            int j = i >> 5, c4 = (i & 31) * 4;
            *(float4*)&sWx[j * 128 + c4] = *(const float4*)&wxp[(size_t)j * 128 + c4];
        }
    }
    float* xcg = ws + O_XC + (size_t)seq * 131072;
    int c3 = (lane >= 3) ? lane - 3 : 64 + lane;
    int c2i = (lane >= 2) ? lane - 2 : 65 + lane;
    int c1 = (lane >= 1) ? lane - 1 : 66;
    for (int dd = 0; dd < 32; ++dd) {
        int d = wq * 32 + dd;                            // uniform
        float4 wc = *(const float4*)&sWc[d * 4];         // uniform LDS broadcast
        int base = d * 68;
        float v = sBc[d] + sXI[base + c3]*wc.x + sXI[base + c2i]*wc.y
                         + sXI[base + c1]*wc.z + sXI[base + lane]*wc.w;
        v = v * sigmoidf_(v);
        sXI[base + lane] = v;
        xcg[(size_t)d * 1024 + p0 + lane] = v;
    }
    __syncthreads();
    // ---- x-proj: 9 j per wave, K=128, weights uniform b128 from LDS ----
    float acc9[9];
#pragma unroll
    for (int jj = 0; jj < 9; ++jj) acc9[jj] = 0.f;
    int jx0 = wq * 9;                                    // uniform
#pragma unroll 4
    for (int c4 = 0; c4 < 32; ++c4) {
        float xv0 = sXI[(c4*4+0) * 68 + lane];
        float xv1 = sXI[(c4*4+1) * 68 + lane];
        float xv2 = sXI[(c4*4+2) * 68 + lane];
        float xv3 = sXI[(c4*4+3) * 68 + lane];
#pragma unroll
        for (int jj = 0; jj < 9; ++jj) {
            float4 w4 = *(const float4*)&sWx[(jx0 + jj) * 128 + c4 * 4];   // uniform
            acc9[jj] += xv0*w4.x + xv1*w4.y + xv2*w4.z + xv3*w4.w;
        }
    }
#pragma unroll
    for (int jj = 0; jj < 9; ++jj) {
        int j = jx0 + jj;                                // uniform
        float v = acc9[jj];
        if (j < 4)       ws[O_DTP + ((size_t)seq * 4 + j) * 1024 + p0 + lane] = v;
        else if (j < 20) ws[O_BM + (size_t)seq * 16384 + (size_t)(j - 4)  * 1024 + p0 + lane] = v;
        else             ws[O_CM + (size_t)seq * 16384 + (size_t)(j - 20) * 1024 + p0 + lane] = v;
    }
}

// ================= k3: chunk-parallel scan, 32 chunks x 32 steps =================
__device__ __forceinline__ void k3_a2(const float* alog, int d0, int s0, float* a2) {
    float4 a0 = *(const float4*)(alog + d0 * 16 + s0);
    float4 a1 = *(const float4*)(alog + (d0 + 1) * 16 + s0);
    a2[0] = -fexp2(a0.x * L2E) * L2E; a2[1] = -fexp2(a0.y * L2E) * L2E;
    a2[2] = -fexp2(a0.z * L2E) * L2E; a2[3] = -fexp2(a0.w * L2E) * L2E;
    a2[4] = -fexp2(a1.x * L2E) * L2E; a2[5] = -fexp2(a1.y * L2E) * L2E;
    a2[6] = -fexp2(a1.z * L2E) * L2E; a2[7] = -fexp2(a1.w * L2E) * L2E;
}

// phase A: local scan (h0=0); emit per-chunk P = exp2(a2*sum_dt) and end E
__global__ __launch_bounds__(256) void k3a_scan(const float* __restrict__ wdt,
                                                const float* __restrict__ bdt,
                                                const float* __restrict__ alog,
                                                float* __restrict__ ws)
{
    __shared__ float sXC[128 * 33];
    __shared__ __align__(16) float sB[32 * 16];
    __shared__ __align__(16) float sDtp[32 * 4];
    int bid = blockIdx.x;
    int seq = bid >> 5, ch = bid & 31;
    int lb = ch * 32;
    int tid = threadIdx.x;
    int d0 = (tid >> 2) * 2, s0 = (tid & 3) * 4;

    float4 wdt0 = *(const float4*)&wdt[d0 * 4];
    float4 wdt1 = *(const float4*)&wdt[(d0 + 1) * 4];
    float bdt0 = bdt[d0], bdt1 = bdt[d0 + 1];
    float a2[8];
    k3_a2(alog, d0, s0, a2);

    const float* xcg = ws + O_XC + (size_t)seq * 131072;
    const float* Bmg = ws + O_BM + (size_t)seq * 16384;
#pragma unroll
    for (int k = 0; k < 16; ++k) {
        int i = tid + k * 256;
        int d = i >> 5, li = i & 31;
        sXC[d * 33 + li] = xcg[(size_t)d * 1024 + lb + li];
    }
#pragma unroll
    for (int k = 0; k < 2; ++k) {
        int i = tid + k * 256;
        int s = i >> 5, li = i & 31;
        sB[li * 16 + s] = Bmg[(size_t)s * 1024 + lb + li];
    }
    if (tid < 128) {
        int li = tid >> 2, j = tid & 3;
        sDtp[li * 4 + j] = ws[O_DTP + ((size_t)seq * 4 + j) * 1024 + lb + li];
    }
    __syncthreads();

    float h[8];
#pragma unroll
    for (int i = 0; i < 8; ++i) h[i] = 0.f;
    float sdt0 = 0.f, sdt1 = 0.f;
    for (int li = 0; li < 32; ++li) {
        float4 q = *(const float4*)&sDtp[li * 4];
        float dt0 = softplusf_(bdt0 + q.x*wdt0.x + q.y*wdt0.y + q.z*wdt0.z + q.w*wdt0.w);
        float dt1 = softplusf_(bdt1 + q.x*wdt1.x + q.y*wdt1.y + q.z*wdt1.z + q.w*wdt1.w);
        float dx0 = dt0 * sXC[d0 * 33 + li], dx1 = dt1 * sXC[(d0 + 1) * 33 + li];
        float4 Bv = *(const float4*)&sB[li * 16 + s0];
        float bv[4] = {Bv.x, Bv.y, Bv.z, Bv.w};
        sdt0 += dt0; sdt1 += dt1;
#pragma unroll
        for (int ss = 0; ss < 4; ++ss) {
            h[ss]     = fexp2(dt0 * a2[ss])     * h[ss]     + dx0 * bv[ss];
            h[4 + ss] = fexp2(dt1 * a2[4 + ss]) * h[4 + ss] + dx1 * bv[ss];
        }
    }
    float* hp = ws + O_HP + (size_t)(seq * 32 + ch) * 4096;
#pragma unroll
    for (int ss = 0; ss < 4; ++ss) {
        hp[d0 * 16 + s0 + ss]              = fexp2(a2[ss] * sdt0);
        hp[(d0 + 1) * 16 + s0 + ss]        = fexp2(a2[4 + ss] * sdt1);
        hp[2048 + d0 * 16 + s0 + ss]       = h[ss];
        hp[2048 + (d0 + 1) * 16 + s0 + ss] = h[4 + ss];
    }
}

// phase B: per-seq sequential prefix compose; h_init overwrites P slot
__global__ __launch_bounds__(256) void k3b_compose(float* __restrict__ ws)
{
    int seq = blockIdx.x;
    int tid = threadIdx.x;
    int d0 = (tid >> 2) * 2, s0 = (tid & 3) * 4;
    int i0 = d0 * 16 + s0, i1 = (d0 + 1) * 16 + s0;
    float h[8];
#pragma unroll
    for (int i = 0; i < 8; ++i) h[i] = 0.f;
    float* hpb = ws + O_HP + (size_t)seq * 32 * 4096;
    for (int c = 0; c < 32; ++c) {
        float* hp = hpb + (size_t)c * 4096;
        float4 P0 = *(const float4*)&hp[i0];
        float4 P1 = *(const float4*)&hp[i1];
        float4 E0 = *(const float4*)&hp[2048 + i0];
        float4 E1 = *(const float4*)&hp[2048 + i1];
        *(float4*)&hp[i0] = make_float4(h[0], h[1], h[2], h[3]);
        *(float4*)&hp[i1] = make_float4(h[4], h[5], h[6], h[7]);
        h[0] = P0.x * h[0] + E0.x; h[1] = P0.y * h[1] + E0.y;
        h[2] = P0.z * h[2] + E0.z; h[3] = P0.w * h[3] + E0.w;
        h[4] = P1.x * h[4] + E1.x; h[5] = P1.y * h[5] + E1.y;
        h[6] = P1.z * h[6] + E1.z; h[7] = P1.w * h[7] + E1.w;
    }
}

// ================= kC: rescan + gate + out-proj + skip (fused) =================
// grid 1024 = 32 seq * 32 chunk; block 256. Out-proj weights LDS-staged [d][c].
__global__ __launch_bounds__(256) void kC_back(
    const float* __restrict__ x0, const float* __restrict__ x1,
    const float* __restrict__ x2, const float* __restrict__ x3,
    const float* __restrict__ g1, const float* __restrict__ be1,
    const float* __restrict__ g2, const float* __restrict__ be2,
    const float* __restrict__ g3, const float* __restrict__ be3,
    const float* __restrict__ g4, const float* __restrict__ be4,
    const float* __restrict__ wdt, const float* __restrict__ bdt,
    const float* __restrict__ alog, const float* __restrict__ dpar,
    const float* __restrict__ woutp, const float* __restrict__ skipp,
    float* __restrict__ ws, float* __restrict__ out)
{
    __shared__ float sXC[128 * 33];   // xc, overwritten by gated g during scan
    __shared__ float sZ[128 * 33];
    __shared__ __align__(16) float sW[128 * 68];   // woutp^T [d][c]
    __shared__ __align__(16) float sB[32 * 16];
    __shared__ __align__(16) float sC[32 * 16];
    __shared__ __align__(16) float sDtp[32 * 4];
    int bid = blockIdx.x;
    int seq = bid >> 5, ch = bid & 31;
    int branch = seq >> 3, b = seq & 7;
    int lb = ch * 32;
    int tid = threadIdx.x;
    int sq = tid & 3;
    int d0 = (tid >> 2) * 2, s0 = sq * 4;

    float4 wdt0 = *(const float4*)&wdt[d0 * 4];
    float4 wdt1 = *(const float4*)&wdt[(d0 + 1) * 4];
    float bdt0 = bdt[d0], bdt1 = bdt[d0 + 1];
    float D0 = dpar[d0], D1 = dpar[d0 + 1];
    float a2[8];
    k3_a2(alog, d0, s0, a2);

    const float* xcg = ws + O_XC + (size_t)seq * 131072;
    const float* zzg = ws + O_Z  + (size_t)seq * 131072;
    const float* Bmg = ws + O_BM + (size_t)seq * 16384;
    const float* Cmg = ws + O_CM + (size_t)seq * 16384;
#pragma unroll
    for (int k = 0; k < 16; ++k) {
        int i = tid + k * 256;
        int d = i >> 5, li = i & 31;
        sXC[d * 33 + li] = xcg[(size_t)d * 1024 + lb + li];
        sZ [d * 33 + li] = zzg[(size_t)d * 1024 + lb + li];
    }
#pragma unroll
    for (int k = 0; k < 2; ++k) {
        int i = tid + k * 256;
        int s = i >> 5, li = i & 31;
        sB[li * 16 + s] = Bmg[(size_t)s * 1024 + lb + li];
        sC[li * 16 + s] = Cmg[(size_t)s * 1024 + lb + li];
    }
    if (tid < 128) {
        int li = tid >> 2, j = tid & 3;
        sDtp[li * 4 + j] = ws[O_DTP + ((size_t)seq * 4 + j) * 1024 + lb + li];
    }
    // stage woutp [64 c][128 d] -> sW [d][68]: thread owns (d, c-quad)
#pragma unroll
    for (int k = 0; k < 8; ++k) {
        int i = tid + k * 256;            // 0..2047
        int d = i >> 4, c4 = (i & 15) * 4;
        float4 v;
        v.x = woutp[(size_t)(c4 + 0) * 128 + d];
        v.y = woutp[(size_t)(c4 + 1) * 128 + d];
        v.z = woutp[(size_t)(c4 + 2) * 128 + d];
        v.w = woutp[(size_t)(c4 + 3) * 128 + d];
        *(float4*)&sW[d * 68 + c4] = v;
    }
    const float* hp = ws + O_HP + (size_t)(seq * 32 + ch) * 4096;
    float4 H0 = *(const float4*)&hp[d0 * 16 + s0];
    float4 H1 = *(const float4*)&hp[(d0 + 1) * 16 + s0];
    float h[8] = {H0.x, H0.y, H0.z, H0.w, H1.x, H1.y, H1.z, H1.w};
    __syncthreads();

    // ---- scan + in-loop gating; g overwrites sXC ----
    for (int li = 0; li < 32; ++li) {
        float4 q = *(const float4*)&sDtp[li * 4];
        float dt0 = softplusf_(bdt0 + q.x*wdt0.x + q.y*wdt0.y + q.z*wdt0.z + q.w*wdt0.w);
        float dt1 = softplusf_(bdt1 + q.x*wdt1.x + q.y*wdt1.y + q.z*wdt1.z + q.w*wdt1.w);
        float xc0 = sXC[d0 * 33 + li], xc1 = sXC[(d0 + 1) * 33 + li];
        float dx0 = dt0 * xc0, dx1 = dt1 * xc1;
        float4 Bv = *(const float4*)&sB[li * 16 + s0];
        float4 Cv = *(const float4*)&sC[li * 16 + s0];
        float bv[4] = {Bv.x, Bv.y, Bv.z, Bv.w};
        float cv[4] = {Cv.x, Cv.y, Cv.z, Cv.w};
        float acc0 = 0.f, acc1 = 0.f;
#pragma unroll
        for (int ss = 0; ss < 4; ++ss) {
            h[ss] = fexp2(dt0 * a2[ss]) * h[ss] + dx0 * bv[ss];
            acc0 += h[ss] * cv[ss];
            h[4 + ss] = fexp2(dt1 * a2[4 + ss]) * h[4 + ss] + dx1 * bv[ss];
            acc1 += h[4 + ss] * cv[ss];
        }
        acc0 += __shfl_xor(acc0, 1); acc0 += __shfl_xor(acc0, 2);
        acc1 += __shfl_xor(acc1, 1); acc1 += __shfl_xor(acc1, 2);
        if (sq == 0) {
            float z0 = sZ[d0 * 33 + li], z1 = sZ[(d0 + 1) * 33 + li];
            sXC[d0 * 33 + li]       = (acc0 + D0 * xc0) * (z0 * sigmoidf_(z0));
            sXC[(d0 + 1) * 33 + li] = (acc1 + D1 * xc1) * (z1 * sigmoidf_(z1));
        }
    }
    __syncthreads();

    // ---- out-proj: thread = (c-octet, col); weights from LDS ----
    int col = tid & 31, c0 = (tid >> 5) * 8;
    float acc8[8];
#pragma unroll
    for (int cc = 0; cc < 8; ++cc) acc8[cc] = 0.f;
#pragma unroll 4
    for (int d = 0; d < 128; ++d) {
        float g = sXC[d * 33 + col];
        float4 wa = *(const float4*)&sW[d * 68 + c0];
        float4 wb = *(const float4*)&sW[d * 68 + c0 + 4];
        acc8[0] += g * wa.x; acc8[1] += g * wa.y;
        acc8[2] += g * wa.z; acc8[3] += g * wa.w;
        acc8[4] += g * wb.x; acc8[5] += g * wb.y;
        acc8[6] += g * wb.z; acc8[7] += g * wb.w;
    }
    // epilogue: + skip * xn (recomputed from stored stats)
    const float* xin = (branch==0)?x0:(branch==1)?x1:(branch==2)?x2:x3;
    const float* gam = (branch==0)?g1:(branch==1)?g2:(branch==2)?g3:g4;
    const float* bet = (branch==0)?be1:(branch==1)?be2:(branch==2)?be3:be4;
    const float* xb = xin + (size_t)b * 65536;
    int colg = lb + col;
    float mean = ws[O_M  + (size_t)seq * 1024 + colg];
    float rs   = ws[O_RS + (size_t)seq * 1024 + colg];
    float skipv = skipp[0];
#pragma unroll
    for (int cc = 0; cc < 8; ++cc) {
        int c = c0 + cc;
        float xv = xb[(size_t)c * 1024 + colg];
        float xn = (xv - mean) * rs * gam[c] + bet[c];
        out[((size_t)b * 256 + branch * 64 + c) * 1024 + colg] = acc8[cc] + skipv * xn;
    }
}

// ---------------- launch ----------------
extern "C" void kernel_launch(void* const* d_in, const int* in_sizes, int n_in,
                              void* d_out, int out_size, void* d_ws, size_t ws_size,
                              hipStream_t stream) {
    float* ws = (float*)d_ws;
    auto f = [&](int i) { return (const float*)d_in[i]; };
    hipLaunchKernelGGL(kA_front, dim3(512), dim3(256), 0, stream,
        f(0), f(1), f(2), f(3), f(13),
        f(4), f(5), f(6), f(7), f(8), f(9), f(10), f(11),
        f(14), f(15), f(16), ws);
    hipLaunchKernelGGL(k3a_scan, dim3(1024), dim3(256), 0, stream, f(17), f(18), f(19), ws);
    hipLaunchKernelGGL(k3b_compose, dim3(32), dim3(256), 0, stream, ws);
    hipLaunchKernelGGL(kC_back, dim3(1024), dim3(256), 0, stream,
        f(0), f(1), f(2), f(3),
        f(4), f(5), f(6), f(7), f(8), f(9), f(10), f(11),
        f(17), f(18), f(19), f(20), f(21), f(12),
        ws, (float*)d_out);
}

// Round 8
// 251.507 us; speedup vs baseline: 1.0426x; 1.0426x over previous
//
#include <hip/hip_runtime.h>
#include <hip/hip_bf16.h>

#define L2E 1.4426950408889634f
#define LN2 0.6931471805599453f

__device__ __forceinline__ float fexp2(float x) { return __builtin_amdgcn_exp2f(x); }
__device__ __forceinline__ float flog2(float x) { return __builtin_amdgcn_logf(x); }
__device__ __forceinline__ int uniform(int x) { return __builtin_amdgcn_readfirstlane(x); }
__device__ __forceinline__ float sigmoidf_(float v) { return 1.f / (1.f + fexp2(-v * L2E)); }
__device__ __forceinline__ float softplusf_(float t) {
    return (t > 20.f) ? t : LN2 * flog2(1.f + fexp2(t * L2E));
}

// ---------------- workspace layout (floats) ----------------
constexpr size_t O_M   = 0;          // [32][1024] LN mean
constexpr size_t O_RS  = 32768;      // [32][1024] LN rstd
constexpr size_t O_Z   = 65536;      // [32][128][1024] z
constexpr size_t O_XC  = 4259840;    // [32][128][1024] conv+silu out
constexpr size_t O_BM  = 8454144;    // [32][16][1024]
constexpr size_t O_CM  = 8978432;    // [32][16][1024]
constexpr size_t O_DTP = 9502720;    // [32][4][1024] dt-proj pre-softplus planes
constexpr size_t O_HP  = 9633792;    // [32][32][2][2048] per-chunk P(->h_init) and E

__device__ __forceinline__ void k3_a2(const float* alog, int d0, int s0, float* a2) {
    float4 a0 = *(const float4*)(alog + d0 * 16 + s0);
    float4 a1 = *(const float4*)(alog + (d0 + 1) * 16 + s0);
    a2[0] = -fexp2(a0.x * L2E) * L2E; a2[1] = -fexp2(a0.y * L2E) * L2E;
    a2[2] = -fexp2(a0.z * L2E) * L2E; a2[3] = -fexp2(a0.w * L2E) * L2E;
    a2[4] = -fexp2(a1.x * L2E) * L2E; a2[5] = -fexp2(a1.y * L2E) * L2E;
    a2[6] = -fexp2(a1.z * L2E) * L2E; a2[7] = -fexp2(a1.w * L2E) * L2E;
}

#define WREDUCE(v) { v += __shfl_xor(v,1); v += __shfl_xor(v,2); v += __shfl_xor(v,4); \
                     v += __shfl_xor(v,8); v += __shfl_xor(v,16); v += __shfl_xor(v,32); }

// ================= kA: LN + in-proj + conv/SiLU + x-proj + LOCAL SCAN (fused) ==========
// grid 1024 = 32 seq * 32 ptile (32 cols = 1 scan chunk); block 256 = 4 waves. ~51 KB LDS.
// sXI row layout: [d][36]: idx 1..3 = halo (p0-3..p0-1), idx 4..35 = main cols.
__global__ __launch_bounds__(256) void kA_front(
    const float* __restrict__ x0, const float* __restrict__ x1,
    const float* __restrict__ x2, const float* __restrict__ x3,
    const float* __restrict__ win,
    const float* __restrict__ g1, const float* __restrict__ be1,
    const float* __restrict__ g2, const float* __restrict__ be2,
    const float* __restrict__ g3, const float* __restrict__ be3,
    const float* __restrict__ g4, const float* __restrict__ be4,
    const float* __restrict__ wconv, const float* __restrict__ bconv,
    const float* __restrict__ wxp,
    const float* __restrict__ wdt, const float* __restrict__ bdt,
    const float* __restrict__ alog,
    float* __restrict__ ws)
{
    __shared__ __align__(16) float sXI[128 * 36];  // xi -> xc
    __shared__ __align__(16) float sU[6400];       // overlays (see pointers below)
    __shared__ __align__(16) float sB2[512];       // [32 li][16 s]
    __shared__ __align__(16) float sDtp2[128];     // [32 li][4]
    __shared__ __align__(16) float sWc[512];
    __shared__ float sBc[128], sGam[64], sBet[64];
    __shared__ float sPs[256], sPq[256], sM[36], sR[36];
    float* sX   = sU;           // [64][36] xn (phases 0-4)
    float* sW   = sU + 2304;    // [64][64] in-proj weight chunk (phase 3)
    float* sWx  = sU;           // [36][128] x-proj weights (phases 5-6)
    float* sP   = sU + 4608;    // [36][32] x-proj outputs (phases 6-7)
    float* sXCt = sU;           // [32][128] xc transposed (phases 7-8)

    int bid = blockIdx.x;
    int seq = bid >> 5, ptile = bid & 31;
    int branch = seq >> 3, b = seq & 7;
    int tid = threadIdx.x;
    int lane = tid & 63;
    int wq = uniform(tid >> 6);
    int jhalf = lane >> 5, col = lane & 31;
    int p0 = ptile * 32;
    const float* xin = (branch==0)?x0:(branch==1)?x1:(branch==2)?x2:x3;
    const float* gam = (branch==0)?g1:(branch==1)?g2:(branch==2)?g3:g4;
    const float* bet = (branch==0)?be1:(branch==1)?be2:(branch==2)?be3:be4;
    const float* xb = xin + (size_t)b * 65536;

    // ---- phase 0: stage small params + raw x (32 cols + 3 halo) ----
    for (int i = tid; i < 512; i += 256) sWc[i] = wconv[i];
    if (tid < 128) sBc[tid] = bconv[tid];
    if (tid < 64) { sGam[tid] = gam[tid]; sBet[tid] = bet[tid]; }
#pragma unroll
    for (int k = 0; k < 2; ++k) {
        int i = tid + k * 256;
        int c = i >> 3, c4 = (i & 7) * 4;
        *(float4*)&sX[c * 36 + 4 + c4] = *(const float4*)&xb[(size_t)c * 1024 + p0 + c4];
    }
    {
        int hc = tid & 3, c = tid >> 2;
        if (hc < 3) sX[c * 36 + 1 + hc] = (ptile > 0) ? xb[(size_t)c * 1024 + p0 - 3 + hc] : 0.f;
    }
    __syncthreads();

    // ---- phase 1: LN stats ----
    {
        int g = tid >> 5;   // 0..7
        float s = 0.f, q = 0.f;
#pragma unroll
        for (int cc = 0; cc < 8; ++cc) {
            float v = sX[(g * 8 + cc) * 36 + 4 + (tid & 31)];
            s += v; q += v * v;
        }
        sPs[g * 32 + (tid & 31)] = s; sPq[g * 32 + (tid & 31)] = q;
    }
    if (ptile > 0 && wq < 3) {   // halo col stats via wave shuffle (lane = c)
        float v = sX[lane * 36 + 1 + wq];
        float s = v, q = v * v;
        WREDUCE(s); WREDUCE(q);
        if (lane == 0) {
            float mean = s * (1.f/64.f);
            float var  = q * (1.f/64.f) - mean * mean;
            sM[1 + wq] = mean; sR[1 + wq] = rsqrtf(var + 1e-5f);
        }
    }
    __syncthreads();
    if (tid < 32) {
        float ss = 0.f, qq = 0.f;
#pragma unroll
        for (int g = 0; g < 8; ++g) { ss += sPs[g * 32 + tid]; qq += sPq[g * 32 + tid]; }
        float mean = ss * (1.f/64.f);
        float var  = qq * (1.f/64.f) - mean * mean;
        float rs   = rsqrtf(var + 1e-5f);
        sM[4 + tid] = mean; sR[4 + tid] = rs;
        ws[O_M  + (size_t)seq * 1024 + p0 + tid] = mean;
        ws[O_RS + (size_t)seq * 1024 + p0 + tid] = rs;
    }
    __syncthreads();

    // ---- phase 2: normalize ----
#pragma unroll
    for (int k = 0; k < 8; ++k) {
        int i = tid + k * 256;
        int c = i >> 5, cl = i & 31;
        float v = sX[c * 36 + 4 + cl];
        sX[c * 36 + 4 + cl] = (v - sM[4 + cl]) * sR[4 + cl] * sGam[c] + sBet[c];
    }
    if (ptile > 0 && wq < 3) {
        int idx = lane * 36 + 1 + wq;
        float v = sX[idx];
        sX[idx] = (v - sM[1 + wq]) * sR[1 + wq] * sGam[lane] + sBet[lane];
    }

    // ---- phase 3: in-proj, 4 chunks of 64 j; weights in LDS ----
    float* zz = ws + O_Z + (size_t)seq * 131072;
    for (int ck = 0; ck < 4; ++ck) {
        __syncthreads();
#pragma unroll
        for (int k = 0; k < 4; ++k) {
            int i = tid + k * 256;
            int jr = i >> 4, c4 = (i & 15) * 4;
            *(float4*)&sW[jr * 64 + c4] = *(const float4*)&win[(size_t)(ck * 64 + jr) * 64 + c4];
        }
        __syncthreads();
        float acc[8];
#pragma unroll
        for (int jj = 0; jj < 8; ++jj) acc[jj] = 0.f;
        int jl0 = wq * 16 + jhalf;
#pragma unroll 2
        for (int c4 = 0; c4 < 16; ++c4) {
            float xv0 = sX[(c4*4+0) * 36 + 4 + col];
            float xv1 = sX[(c4*4+1) * 36 + 4 + col];
            float xv2 = sX[(c4*4+2) * 36 + 4 + col];
            float xv3 = sX[(c4*4+3) * 36 + 4 + col];
#pragma unroll
            for (int jj = 0; jj < 8; ++jj) {
                float4 w4 = *(const float4*)&sW[(jl0 + jj * 2) * 64 + c4 * 4];
                acc[jj] += xv0*w4.x + xv1*w4.y + xv2*w4.z + xv3*w4.w;
            }
        }
#pragma unroll
        for (int jj = 0; jj < 8; ++jj) {
            int j = ck * 64 + jl0 + jj * 2;
            if (j < 128) sXI[j * 36 + 4 + col] = acc[jj];
            else         zz[(size_t)(j - 128) * 1024 + p0 + col] = acc[jj];
        }
    }
    __syncthreads();

    // ---- phase 4: halo xi (3 cols x 128 j) via wave shuffle, or zero-fill ----
    if (ptile > 0) {
        for (int jj = 0; jj < 32; ++jj) {
            int j = wq * 32 + jj;                    // uniform
            float w = win[(size_t)j * 64 + lane];    // coalesced
            float a0 = w * sX[lane * 36 + 1];
            float a1 = w * sX[lane * 36 + 2];
            float a2v = w * sX[lane * 36 + 3];
            WREDUCE(a0); WREDUCE(a1); WREDUCE(a2v);
            if (lane == 0) {
                sXI[j * 36 + 1] = a0;
                sXI[j * 36 + 2] = a1;
                sXI[j * 36 + 3] = a2v;
            }
        }
    } else {
#pragma unroll
        for (int k = 0; k < 2; ++k) {
            int i = tid + k * 256;
            int d = i >> 2, hc = i & 3;
            if (hc < 3) sXI[d * 36 + 1 + hc] = 0.f;
        }
    }
    __syncthreads();

    // ---- phase 5: stage x-proj weights (overlay) + conv4 + SiLU in place ----
#pragma unroll
    for (int k = 0; k < 5; ++k) {
        int i = tid + k * 256;
        if (i < 1152) {
            int j = i >> 5, c4 = (i & 31) * 4;
            *(float4*)&sWx[j * 128 + c4] = *(const float4*)&wxp[(size_t)j * 128 + c4];
        }
    }
    float* xcg = ws + O_XC + (size_t)seq * 131072;
#pragma unroll 2
    for (int k = 0; k < 16; ++k) {
        int d = wq * 32 + k * 2 + jhalf;             // 2-addr per wave
        float4 wc = *(const float4*)&sWc[d * 4];
        int base = d * 36 + 1 + col;
        float v = sBc[d] + sXI[base]*wc.x + sXI[base+1]*wc.y
                         + sXI[base+2]*wc.z + sXI[base+3]*wc.w;
        v = v * sigmoidf_(v);
        sXI[d * 36 + 4 + col] = v;
        xcg[(size_t)d * 1024 + p0 + col] = v;
    }
    __syncthreads();

    // ---- phase 6: x-proj (36 j, K=128 split across lane halves) ----
    float acc9[9];
#pragma unroll
    for (int jj = 0; jj < 9; ++jj) acc9[jj] = 0.f;
    int jx0 = wq * 9;                                // uniform
    int cb = jhalf * 64;
#pragma unroll 2
    for (int c4 = 0; c4 < 16; ++c4) {
        int c = cb + c4 * 4;
        float xv0 = sXI[(c+0) * 36 + 4 + col];
        float xv1 = sXI[(c+1) * 36 + 4 + col];
        float xv2 = sXI[(c+2) * 36 + 4 + col];
        float xv3 = sXI[(c+3) * 36 + 4 + col];
#pragma unroll
        for (int jj = 0; jj < 9; ++jj) {
            float4 w4 = *(const float4*)&sWx[(jx0 + jj) * 128 + c];
            acc9[jj] += xv0*w4.x + xv1*w4.y + xv2*w4.z + xv3*w4.w;
        }
    }
#pragma unroll
    for (int jj = 0; jj < 9; ++jj) acc9[jj] += __shfl_xor(acc9[jj], 32);
    if (lane < 32) {
#pragma unroll
        for (int jj = 0; jj < 9; ++jj) {
            int j = jx0 + jj;                        // uniform
            float v = acc9[jj];
            sP[j * 32 + col] = v;
            if (j < 4)       ws[O_DTP + ((size_t)seq * 4 + j) * 1024 + p0 + col] = v;
            else if (j < 20) ws[O_BM + (size_t)seq * 16384 + (size_t)(j - 4)  * 1024 + p0 + col] = v;
            else             ws[O_CM + (size_t)seq * 16384 + (size_t)(j - 20) * 1024 + p0 + col] = v;
        }
    }
    __syncthreads();

    // ---- phase 7: transposes for scan (sWx dead; sP still live at sU+4608) ----
#pragma unroll
    for (int k = 0; k < 2; ++k) {
        int i = tid + k * 256;
        int li = i & 31, s = i >> 5;
        sB2[li * 16 + s] = sP[(4 + s) * 32 + li];
    }
    if (tid < 128) {
        int li = tid >> 2, jq = tid & 3;
        sDtp2[li * 4 + jq] = sP[jq * 32 + li];
    }
#pragma unroll
    for (int k = 0; k < 16; ++k) {
        int i = tid + k * 256;
        int li = i >> 7, d = i & 127;
        sXCt[li * 128 + d] = sXI[d * 36 + 4 + li];
    }
    __syncthreads();

    // ---- phase 8: local chunk scan (h0=0), emit P = exp2(a2*sum_dt) and end E ----
    {
        int sq = tid & 3, s0 = sq * 4, d0 = (tid >> 2) * 2;
        float4 wdt0 = *(const float4*)&wdt[d0 * 4];
        float4 wdt1 = *(const float4*)&wdt[(d0 + 1) * 4];
        float bdt0 = bdt[d0], bdt1 = bdt[d0 + 1];
        float a2[8];
        k3_a2(alog, d0, s0, a2);
        float h[8];
#pragma unroll
        for (int i = 0; i < 8; ++i) h[i] = 0.f;
        float sdt0 = 0.f, sdt1 = 0.f;
        for (int li = 0; li < 32; ++li) {
            float4 q = *(const float4*)&sDtp2[li * 4];
            float dt0 = softplusf_(bdt0 + q.x*wdt0.x + q.y*wdt0.y + q.z*wdt0.z + q.w*wdt0.w);
            float dt1 = softplusf_(bdt1 + q.x*wdt1.x + q.y*wdt1.y + q.z*wdt1.z + q.w*wdt1.w);
            float2 xc2 = *(const float2*)&sXCt[li * 128 + d0];
            float dx0 = dt0 * xc2.x, dx1 = dt1 * xc2.y;
            float4 Bv = *(const float4*)&sB2[li * 16 + s0];
            float bv[4] = {Bv.x, Bv.y, Bv.z, Bv.w};
            sdt0 += dt0; sdt1 += dt1;
#pragma unroll
            for (int ss = 0; ss < 4; ++ss) {
                h[ss]     = fexp2(dt0 * a2[ss])     * h[ss]     + dx0 * bv[ss];
                h[4 + ss] = fexp2(dt1 * a2[4 + ss]) * h[4 + ss] + dx1 * bv[ss];
            }
        }
        float* hp = ws + O_HP + (size_t)(seq * 32 + ptile) * 4096;
        *(float4*)&hp[d0 * 16 + s0] =
            make_float4(fexp2(a2[0]*sdt0), fexp2(a2[1]*sdt0), fexp2(a2[2]*sdt0), fexp2(a2[3]*sdt0));
        *(float4*)&hp[(d0 + 1) * 16 + s0] =
            make_float4(fexp2(a2[4]*sdt1), fexp2(a2[5]*sdt1), fexp2(a2[6]*sdt1), fexp2(a2[7]*sdt1));
        *(float4*)&hp[2048 + d0 * 16 + s0]       = make_float4(h[0], h[1], h[2], h[3]);
        *(float4*)&hp[2048 + (d0 + 1) * 16 + s0] = make_float4(h[4], h[5], h[6], h[7]);
    }
}

// ================= k3b: per-seq sequential prefix compose; h_init overwrites P ==========
__global__ __launch_bounds__(256) void k3b_compose(float* __restrict__ ws)
{
    int seq = blockIdx.x;
    int tid = threadIdx.x;
    int d0 = (tid >> 2) * 2, s0 = (tid & 3) * 4;
    int i0 = d0 * 16 + s0, i1 = (d0 + 1) * 16 + s0;
    float h[8];
#pragma unroll
    for (int i = 0; i < 8; ++i) h[i] = 0.f;
    float* hpb = ws + O_HP + (size_t)seq * 32 * 4096;
    for (int c = 0; c < 32; ++c) {
        float* hp = hpb + (size_t)c * 4096;
        float4 P0 = *(const float4*)&hp[i0];
        float4 P1 = *(const float4*)&hp[i1];
        float4 E0 = *(const float4*)&hp[2048 + i0];
        float4 E1 = *(const float4*)&hp[2048 + i1];
        *(float4*)&hp[i0] = make_float4(h[0], h[1], h[2], h[3]);
        *(float4*)&hp[i1] = make_float4(h[4], h[5], h[6], h[7]);
        h[0] = P0.x * h[0] + E0.x; h[1] = P0.y * h[1] + E0.y;
        h[2] = P0.z * h[2] + E0.z; h[3] = P0.w * h[3] + E0.w;
        h[4] = P1.x * h[4] + E1.x; h[5] = P1.y * h[5] + E1.y;
        h[6] = P1.z * h[6] + E1.z; h[7] = P1.w * h[7] + E1.w;
    }
}

// ================= kC: rescan + gate (streamed z) + out-proj + skip ==========
// grid 1024 = 32 seq * 32 chunk; block 256; ~38 KB LDS -> 4 blocks/CU.
__global__ __launch_bounds__(256) void kC_back(
    const float* __restrict__ x0, const float* __restrict__ x1,
    const float* __restrict__ x2, const float* __restrict__ x3,
    const float* __restrict__ g1, const float* __restrict__ be1,
    const float* __restrict__ g2, const float* __restrict__ be2,
    const float* __restrict__ g3, const float* __restrict__ be3,
    const float* __restrict__ g4, const float* __restrict__ be4,
    const float* __restrict__ wdt, const float* __restrict__ bdt,
    const float* __restrict__ alog, const float* __restrict__ dpar,
    const float* __restrict__ woutp, const float* __restrict__ skipp,
    float* __restrict__ ws, float* __restrict__ out)
{
    __shared__ float sXC[128 * 33];                 // xc -> y' -> gated g
    __shared__ __align__(16) float sW[64 * 64];     // out-proj weight half, [dd][c]
    __shared__ __align__(16) float sB[512], sC[512], sDtp[128];
    int bid = blockIdx.x;
    int seq = bid >> 5, ch = bid & 31;
    int branch = seq >> 3, b = seq & 7;
    int lb = ch * 32;
    int tid = threadIdx.x;
    int sq = tid & 3, s0 = sq * 4, d0 = (tid >> 2) * 2;

    float4 wdt0 = *(const float4*)&wdt[d0 * 4];
    float4 wdt1 = *(const float4*)&wdt[(d0 + 1) * 4];
    float bdt0 = bdt[d0], bdt1 = bdt[d0 + 1];
    float D0 = dpar[d0], D1 = dpar[d0 + 1];
    float a2[8];
    k3_a2(alog, d0, s0, a2);

    const float* xcg = ws + O_XC + (size_t)seq * 131072;
    const float* Bmg = ws + O_BM + (size_t)seq * 16384;
    const float* Cmg = ws + O_CM + (size_t)seq * 16384;
#pragma unroll
    for (int k = 0; k < 16; ++k) {
        int i = tid + k * 256;
        int d = i >> 5, li = i & 31;
        sXC[d * 33 + li] = xcg[(size_t)d * 1024 + lb + li];
    }
#pragma unroll
    for (int k = 0; k < 2; ++k) {
        int i = tid + k * 256;
        int s = i >> 5, li = i & 31;
        sB[li * 16 + s] = Bmg[(size_t)s * 1024 + lb + li];
        sC[li * 16 + s] = Cmg[(size_t)s * 1024 + lb + li];
    }
    if (tid < 128) {
        int li = tid >> 2, j = tid & 3;
        sDtp[li * 4 + j] = ws[O_DTP + ((size_t)seq * 4 + j) * 1024 + lb + li];
    }
    const float* hp = ws + O_HP + (size_t)(seq * 32 + ch) * 4096;
    float4 H0 = *(const float4*)&hp[d0 * 16 + s0];
    float4 H1 = *(const float4*)&hp[(d0 + 1) * 16 + s0];
    float h[8] = {H0.x, H0.y, H0.z, H0.w, H1.x, H1.y, H1.z, H1.w};
    __syncthreads();

    // ---- scan; write y' = acc + D*xc back into sXC ----
    for (int li = 0; li < 32; ++li) {
        float4 q = *(const float4*)&sDtp[li * 4];
        float dt0 = softplusf_(bdt0 + q.x*wdt0.x + q.y*wdt0.y + q.z*wdt0.z + q.w*wdt0.w);
        float dt1 = softplusf_(bdt1 + q.x*wdt1.x + q.y*wdt1.y + q.z*wdt1.z + q.w*wdt1.w);
        float xc0 = sXC[d0 * 33 + li], xc1 = sXC[(d0 + 1) * 33 + li];
        float dx0 = dt0 * xc0, dx1 = dt1 * xc1;
        float4 Bv = *(const float4*)&sB[li * 16 + s0];
        float4 Cv = *(const float4*)&sC[li * 16 + s0];
        float bv[4] = {Bv.x, Bv.y, Bv.z, Bv.w};
        float cv[4] = {Cv.x, Cv.y, Cv.z, Cv.w};
        float acc0 = 0.f, acc1 = 0.f;
#pragma unroll
        for (int ss = 0; ss < 4; ++ss) {
            h[ss] = fexp2(dt0 * a2[ss]) * h[ss] + dx0 * bv[ss];
            acc0 += h[ss] * cv[ss];
            h[4 + ss] = fexp2(dt1 * a2[4 + ss]) * h[4 + ss] + dx1 * bv[ss];
            acc1 += h[4 + ss] * cv[ss];
        }
        acc0 += __shfl_xor(acc0, 1); acc0 += __shfl_xor(acc0, 2);
        acc1 += __shfl_xor(acc1, 1); acc1 += __shfl_xor(acc1, 2);
        if (sq == 0) {
            sXC[d0 * 33 + li]       = acc0 + D0 * xc0;
            sXC[(d0 + 1) * 33 + li] = acc1 + D1 * xc1;
        }
    }
    __syncthreads();

    // ---- gate with streamed z ----
    const float* zzg = ws + O_Z + (size_t)seq * 131072;
#pragma unroll
    for (int k = 0; k < 16; ++k) {
        int i = tid + k * 256;
        int d = i >> 5, li = i & 31;
        float z = zzg[(size_t)d * 1024 + lb + li];
        sXC[d * 33 + li] = sXC[d * 33 + li] * (z * sigmoidf_(z));
    }

    // ---- out-proj: K=128 in 2 weight halves; thread = (c-octet, col) ----
    int col = tid & 31, c0 = (tid >> 5) * 8;
    float acc8[8];
#pragma unroll
    for (int cc = 0; cc < 8; ++cc) acc8[cc] = 0.f;
    for (int hf = 0; hf < 2; ++hf) {
        __syncthreads();
#pragma unroll
        for (int k = 0; k < 4; ++k) {
            int i = tid + k * 256;
            int dd = i >> 4, c4 = (i & 15) * 4;
            float4 v;
            v.x = woutp[(size_t)(c4 + 0) * 128 + hf * 64 + dd];
            v.y = woutp[(size_t)(c4 + 1) * 128 + hf * 64 + dd];
            v.z = woutp[(size_t)(c4 + 2) * 128 + hf * 64 + dd];
            v.w = woutp[(size_t)(c4 + 3) * 128 + hf * 64 + dd];
            *(float4*)&sW[dd * 64 + c4] = v;
        }
        __syncthreads();
#pragma unroll 4
        for (int dd = 0; dd < 64; ++dd) {
            float g = sXC[(hf * 64 + dd) * 33 + col];
            float4 wa = *(const float4*)&sW[dd * 64 + c0];
            float4 wb = *(const float4*)&sW[dd * 64 + c0 + 4];
            acc8[0] += g * wa.x; acc8[1] += g * wa.y;
            acc8[2] += g * wa.z; acc8[3] += g * wa.w;
            acc8[4] += g * wb.x; acc8[5] += g * wb.y;
            acc8[6] += g * wb.z; acc8[7] += g * wb.w;
        }
    }

    // ---- epilogue: + skip * xn (recomputed from stored stats) ----
    const float* xin = (branch==0)?x0:(branch==1)?x1:(branch==2)?x2:x3;
    const float* gam = (branch==0)?g1:(branch==1)?g2:(branch==2)?g3:g4;
    const float* bet = (branch==0)?be1:(branch==1)?be2:(branch==2)?be3:be4;
    const float* xb = xin + (size_t)b * 65536;
    int colg = lb + col;
    float mean = ws[O_M  + (size_t)seq * 1024 + colg];
    float rs   = ws[O_RS + (size_t)seq * 1024 + colg];
    float skipv = skipp[0];
#pragma unroll
    for (int cc = 0; cc < 8; ++cc) {
        int c = c0 + cc;
        float xv = xb[(size_t)c * 1024 + colg];
        float xn = (xv - mean) * rs * gam[c] + bet[c];
        out[((size_t)b * 256 + branch * 64 + c) * 1024 + colg] = acc8[cc] + skipv * xn;
    }
}

// ---------------- launch ----------------
extern "C" void kernel_launch(void* const* d_in, const int* in_sizes, int n_in,
                              void* d_out, int out_size, void* d_ws, size_t ws_size,
                              hipStream_t stream) {
    float* ws = (float*)d_ws;
    auto f = [&](int i) { return (const float*)d_in[i]; };
    hipLaunchKernelGGL(kA_front, dim3(1024), dim3(256), 0, stream,
        f(0), f(1), f(2), f(3), f(13),
        f(4), f(5), f(6), f(7), f(8), f(9), f(10), f(11),
        f(14), f(15), f(16), f(17), f(18), f(19), ws);
    hipLaunchKernelGGL(k3b_compose, dim3(32), dim3(256), 0, stream, ws);
    hipLaunchKernelGGL(kC_back, dim3(1024), dim3(256), 0, stream,
        f(0), f(1), f(2), f(3),
        f(4), f(5), f(6), f(7), f(8), f(9), f(10), f(11),
        f(17), f(18), f(19), f(20), f(21), f(12),
        ws, (float*)d_out);
}